// Round 8
// baseline (234.470 us; speedup 1.0000x reference)
//
#include <hip/hip_runtime.h>
#include <hip/hip_bf16.h>
#include <math.h>

#define NN 8192      // nodes
#define NK 64        // clusters
#define EPSF 1e-6f
// pass_e: 1024 blocks x 256 threads; block = 8-row band x all cols.
// Wave w sweeps j-quarter [2048w, 2048w+2048) in 8 tiles of 256 cols,
// start-rotated by (bid & 7). Wave-private LDS tile, no barriers in loop.

typedef __attribute__((ext_vector_type(8))) short s16x8;
typedef __attribute__((ext_vector_type(4))) short s16x4;
typedef __attribute__((ext_vector_type(4))) float f32x4;

static __device__ __forceinline__ short f2bf(float x) {
    union { float f; unsigned u; } v; v.f = x;
    unsigned r = (v.u + 0x7fffu + ((v.u >> 16) & 1u)) >> 16;
    return (short)r;
}

// ---------- pre-kernel: A [N][64] f32 -> ATF fragment-major bf16 ----------
// ATF[((chunk*4 + nf)*64 + l)*8 + e] = bf16(A[chunk*32 + 8*(l>>4) + e][16*nf + (l&15)])
// (verified R6: B-frag k = 8*(l>>4)+e, col = l&15)
__global__ __launch_bounds__(256) void cvt_at(const float* __restrict__ A,
                                              unsigned short* __restrict__ ATF) {
    __shared__ unsigned short T[64][72];   // [k][node-local]
    int tid = threadIdx.x;
    int n0 = blockIdx.x * 64;
    int node = tid >> 2;
    int k4 = (tid & 3) << 4;
    const float* ap = A + (size_t)(n0 + node) * NK + k4;
    f32x4 x0 = *(const f32x4*)(ap);
    f32x4 x1 = *(const f32x4*)(ap + 4);
    f32x4 x2 = *(const f32x4*)(ap + 8);
    f32x4 x3 = *(const f32x4*)(ap + 12);
#pragma unroll
    for (int e = 0; e < 4; ++e) {
        T[k4 + e][node]      = (unsigned short)f2bf(x0[e]);
        T[k4 + 4 + e][node]  = (unsigned short)f2bf(x1[e]);
        T[k4 + 8 + e][node]  = (unsigned short)f2bf(x2[e]);
        T[k4 + 12 + e][node] = (unsigned short)f2bf(x3[e]);
    }
    __syncthreads();
#pragma unroll
    for (int pass = 0; pass < 2; ++pass) {
        int oi = pass * 256 + tid;              // 512 outputs x 16B
        int l = oi & 63, nf = (oi >> 6) & 3, cl = oi >> 8;
        int k = (l & 15) + 16 * nf;
        int nb = cl * 32 + (l >> 4) * 8;
        s16x8 v;
#pragma unroll
        for (int e = 0; e < 8; ++e) v[e] = (short)T[k][nb + e];
        size_t chunk = (size_t)blockIdx.x * 2 + cl;
        *(s16x8*)(ATF + ((chunk * 4 + nf) * 64 + l) * 8) = v;
    }
}

// ---------- main pass: row-band streaming, wave-independent ----------
__global__ __launch_bounds__(256, 4) void pass_e(
    const float* __restrict__ E, const float* __restrict__ A,
    const unsigned short* __restrict__ ATF,
    float* __restrict__ rowsum, float* __restrict__ colsum,
    float* __restrict__ within_part)
{
    __shared__ unsigned short Ebf[4][4096];  // per-wave 8KB: [16 rows][256 cols], XOR-swizzled
    __shared__ float rsum[8];
    __shared__ float red[4];

    int tid = threadIdx.x;
    int w = tid >> 6, l = tid & 63;
    int bid = blockIdx.x;
    int band0 = bid * 8;
    int lm = l & 15, lg = l >> 4;
    int rot = bid & 7;

    if (tid < 8) rsum[tid] = 0.f;

    char* buf = (char*)&Ebf[w][0];
    // zero pad rows 8..15 once (zeros are swizzle-invariant)
    {
        s16x4 z = {0, 0, 0, 0};
#pragma unroll
        for (int q = 0; q < 8; ++q)
            *(s16x4*)(buf + 4096 + q * 512 + 8 * l) = z;
    }
    __syncthreads();   // rsum init + pad-zero visible before epilogue adds

    f32x4 D0 = {0.f,0.f,0.f,0.f}, D1 = D0, D2 = D0, D3 = D0, Dr = D0;
    s16x8 ONES;
#pragma unroll
    for (int e = 0; e < 8; ++e) ONES[e] = (short)0x3F80;  // bf16 1.0

    const float* erow = E + (size_t)band0 * NN + 4 * l;
    unsigned wrsw = 8u * (unsigned)l;

    f32x4 ld[8];
    {
        int jc0 = (8 * w + rot) * 256;
#pragma unroll
        for (int q = 0; q < 8; ++q) ld[q] = *(const f32x4*)(erow + (size_t)q * NN + jc0);
    }

    for (int tv = 0; tv < 8; ++tv) {
        int tile = 8 * w + ((rot + tv) & 7);
        int jc = tile * 256;

        // ---- stage: colsum partials in regs, cvt, wave-private ds_write ----
        float c0 = 0.f, c1 = 0.f, c2 = 0.f, c3 = 0.f;
#pragma unroll
        for (int q = 0; q < 8; ++q) {
            f32x4 v = ld[q];
            c0 += v[0]; c1 += v[1]; c2 += v[2]; c3 += v[3];
            s16x4 b; b[0] = f2bf(v[0]); b[1] = f2bf(v[1]); b[2] = f2bf(v[2]); b[3] = f2bf(v[3]);
            *(s16x4*)(buf + q * 512 + (wrsw ^ (16u * (unsigned)q))) = b;
        }
        // ---- issue next tile's loads (sequential per row-stream) ----
        if (tv + 1 < 8) {
            int jn = (8 * w + ((rot + tv + 1) & 7)) * 256;
#pragma unroll
            for (int q = 0; q < 8; ++q) ld[q] = *(const f32x4*)(erow + (size_t)q * NN + jn);
        }
        // ---- colsum: 4 coalesced atomics per lane (8-row partials) ----
        atomicAdd(&colsum[jc + 4 * l + 0], c0);
        atomicAdd(&colsum[jc + 4 * l + 1], c1);
        atomicAdd(&colsum[jc + 4 * l + 2], c2);
        atomicAdd(&colsum[jc + 4 * l + 3], c3);

        // ---- MFMA: 8 chunks of K=32 cols; M[i,k] accumulates in D ----
#pragma unroll
        for (int c = 0; c < 8; ++c) {
            s16x8 af = *(const s16x8*)(buf + lm * 512 + (((unsigned)(c * 64 + 16 * lg)) ^ (16u * (unsigned)(lm & 7))));
            size_t chk = (size_t)(tile * 8 + c);
            const unsigned short* ab = ATF + (chk * 4) * 512 + (size_t)l * 8;
            s16x8 b0 = *(const s16x8*)(ab);
            s16x8 b1 = *(const s16x8*)(ab + 512);
            s16x8 b2 = *(const s16x8*)(ab + 1024);
            s16x8 b3 = *(const s16x8*)(ab + 1536);
            D0 = __builtin_amdgcn_mfma_f32_16x16x32_bf16(af, b0, D0, 0, 0, 0);
            D1 = __builtin_amdgcn_mfma_f32_16x16x32_bf16(af, b1, D1, 0, 0, 0);
            D2 = __builtin_amdgcn_mfma_f32_16x16x32_bf16(af, b2, D2, 0, 0, 0);
            D3 = __builtin_amdgcn_mfma_f32_16x16x32_bf16(af, b3, D3, 0, 0, 0);
            Dr = __builtin_amdgcn_mfma_f32_16x16x32_bf16(af, ONES, Dr, 0, 0, 0);
        }
    }

    // ---- epilogue ----
    // rowsum: Dr[r] = Σ_j(quarter) E[band row 4lg+r][j], identical across lm
    if (lm == 0 && lg < 2) {
#pragma unroll
        for (int r = 0; r < 4; ++r) atomicAdd(&rsum[4 * lg + r], Dr[r]);
    }
    // within: wsum = Σ D[i,k]·A[band0+i][k] (rows 8..15 are zero-pad)
    float wsum = 0.f;
    if (lg < 2) {
        const float* Ab = A + (size_t)(band0 + 4 * lg) * NK + lm;
#pragma unroll
        for (int r = 0; r < 4; ++r) {
            const float* ar = Ab + (size_t)r * NK;
            wsum += D0[r] * ar[0] + D1[r] * ar[16] + D2[r] * ar[32] + D3[r] * ar[48];
        }
    }
#pragma unroll
    for (int m = 1; m < 64; m <<= 1) wsum += __shfl_xor(wsum, m);
    if (l == 0) red[w] = wsum;
    __syncthreads();
    if (tid < 8) rowsum[band0 + tid] = rsum[tid];          // plain store: block owns band
    if (tid == 0) within_part[bid] = red[0] + red[1] + red[2] + red[3];
}

// ---------- spatial pass 1: argmax ids + counts + coord sums ----------
__global__ __launch_bounds__(256) void spatial1(
    const float* __restrict__ A, const float* __restrict__ pos,
    int* __restrict__ ids, float* __restrict__ counts, float* __restrict__ sums)
{
    int wv = threadIdx.x >> 6, l = threadIdx.x & 63;
    int node = blockIdx.x * 4 + wv;
    float v = A[(size_t)node * NK + l];
    int idx = l;
#pragma unroll
    for (int m = 1; m < 64; m <<= 1) {
        float ov = __shfl_xor(v, m);
        int oi = __shfl_xor(idx, m);
        if (ov > v || (ov == v && oi < idx)) { v = ov; idx = oi; }
    }
    if (l == 0) {
        ids[node] = idx;
        atomicAdd(&counts[idx], 1.0f);
        atomicAdd(&sums[idx * 2 + 0], pos[(size_t)node * 2 + 0]);
        atomicAdd(&sums[idx * 2 + 1], pos[(size_t)node * 2 + 1]);
    }
}

// ---------- spatial pass 2: distances to centroids ----------
__global__ __launch_bounds__(256) void spatial2(
    const int* __restrict__ ids, const float* __restrict__ pos,
    const float* __restrict__ counts, const float* __restrict__ sums,
    float* __restrict__ distsum, int* __restrict__ maxid)
{
    __shared__ float ds[64];
    __shared__ int mx;
    int tid = threadIdx.x;
    if (tid < 64) ds[tid] = 0.f;
    if (tid == 0) mx = 0;
    __syncthreads();
    int i = blockIdx.x * 256 + tid;
    int id = ids[i];
    float den = counts[id] + EPSF;
    float cx = sums[id * 2 + 0] / den;
    float cy = sums[id * 2 + 1] / den;
    float dx = pos[(size_t)i * 2 + 0] - cx;
    float dy = pos[(size_t)i * 2 + 1] - cy;
    atomicAdd(&ds[id], sqrtf(dx * dx + dy * dy));
    atomicMax(&mx, id);
    __syncthreads();
    if (tid < 64) atomicAdd(&distsum[tid], ds[tid]);
    if (tid == 0) atomicMax(maxid, mx);
}

// ---------- finalize ----------
__global__ __launch_bounds__(256) void finalize(
    const float* __restrict__ rowsum, const float* __restrict__ colsum,
    const float* __restrict__ cons, const float* __restrict__ gen,
    const float* __restrict__ within_part, const float* __restrict__ counts,
    const float* __restrict__ distsum, const int* __restrict__ maxid,
    float* __restrict__ out)
{
    __shared__ float redb[4], rede[4], redw[4];
    int tid = threadIdx.x;
    int w = tid >> 6, l = tid & 63;
    float bacc = 0.f, eacc = 0.f, wacc = 0.f;
    for (int i = tid; i < NN; i += 256) {
        float imb = (cons[i] - gen[i]) - (colsum[i] - rowsum[i]);
        bacc += imb * imb;
        eacc += rowsum[i];
    }
    for (int i = tid; i < 1024; i += 256) wacc += within_part[i];
#pragma unroll
    for (int m = 1; m < 64; m <<= 1) {
        bacc += __shfl_xor(bacc, m);
        eacc += __shfl_xor(eacc, m);
        wacc += __shfl_xor(wacc, m);
    }
    if (l == 0) { redb[w] = bacc; rede[w] = eacc; redw[w] = wacc; }
    __syncthreads();

    float sacc = 0.f;
    if (tid < 64) {
        float c = counts[tid];
        float avg = distsum[tid] / (c + EPSF);
        sacc = (c >= 2.0f) ? avg : 0.f;
#pragma unroll
        for (int m = 1; m < 64; m <<= 1) sacc += __shfl_xor(sacc, m);
    }
    if (tid == 0) {
        float balance = (redb[0] + redb[1] + redb[2] + redb[3]) / (float)NN;
        float sumE = rede[0] + rede[1] + rede[2] + rede[3];
        float W = redw[0] + redw[1] + redw[2] + redw[3];
        float clustering = (sumE - 2.0f * W) / ((float)NN * (float)NN + EPSF);
        float nc = (float)(maxid[0] + 1) + EPSF;
        float spatial = sacc / nc;
        float total = 1.0f * balance + 0.5f * spatial + 0.3f * clustering;
        out[0] = total;
        out[1] = balance;
        out[2] = spatial;
        out[3] = clustering;
    }
}

extern "C" void kernel_launch(void* const* d_in, const int* in_sizes, int n_in,
                              void* d_out, int out_size, void* d_ws, size_t ws_size,
                              hipStream_t stream) {
    const float* E    = (const float*)d_in[0];
    const float* A    = (const float*)d_in[1];
    const float* pos  = (const float*)d_in[2];
    const float* cons = (const float*)d_in[3];
    const float* gen  = (const float*)d_in[4];
    float* out = (float*)d_out;

    char* ws = (char*)d_ws;
    unsigned short* ATF = (unsigned short*)ws;                // 1 MB fragment-major
    float* rowsum      = (float*)(ws + (size_t)2 * NK * NN);  // [N]
    float* colsum      = rowsum + NN;                         // [N]
    float* counts      = colsum + NN;                         // [64]
    float* sums        = counts + 64;                         // [64][2]
    float* distsum     = sums + 128;                          // [64]
    int*   maxid       = (int*)(distsum + 64);                // [1]
    float* within_part = (float*)(maxid + 1);                 // [1024]
    int*   ids         = (int*)(within_part + 1024);          // [N]

    size_t zbytes = ((size_t)NN * 2 + 64 + 128 + 64 + 1) * 4;
    hipMemsetAsync(rowsum, 0, zbytes, stream);

    cvt_at  <<<NN / 64, 256, 0, stream>>>(A, ATF);
    pass_e  <<<NN / 8, 256, 0, stream>>>(E, A, ATF, rowsum, colsum, within_part);
    spatial1<<<NN / 4, 256, 0, stream>>>(A, pos, ids, counts, sums);
    spatial2<<<NN / 256, 256, 0, stream>>>(ids, pos, counts, sums, distsum, maxid);
    finalize<<<1, 256, 0, stream>>>(rowsum, colsum, cons, gen, within_part, counts, distsum, maxid, out);
}